// Round 14
// baseline (193.821 us; speedup 1.0000x reference)
//
#include <hip/hip_runtime.h>
#include <hip/hip_bf16.h>
#include <math.h>

typedef _Float16 half8  __attribute__((ext_vector_type(8)));
typedef __fp16   fp16x2 __attribute__((ext_vector_type(2)));
typedef float    floatx4 __attribute__((ext_vector_type(4)));

#define IN_CH 64
#define HID   128
#define NSEG  4096

__device__ __forceinline__ unsigned fkey(float s) {
    unsigned u = __float_as_uint(s);
    return (u & 0x80000000u) ? ~u : (u | 0x80000000u);
}
__device__ __forceinline__ float funkey(unsigned k) {
    unsigned u = (k & 0x80000000u) ? (k ^ 0x80000000u) : ~k;
    return __uint_as_float(u);
}

// ---------------- init segment scratch ----------------
__global__ void init_seg(unsigned* __restrict__ segkey, float* __restrict__ denom) {
    int i = blockIdx.x * blockDim.x + threadIdx.x;
    if (i < NSEG) { segkey[i] = 0u; denom[i] = 0.0f; }
}

// ---------------- fused MLP -> scores ----------------
// R6-verified swapped-operand MFMA core. R13/R14: TRUE depth-3 register
// pipeline. R12's VGPR=116 proved the compiler sinks prefetch loads below the
// consuming CORE (pressure heuristic) -> pipeline collapse. Fix: 3-regset
// rotation with sched_group_barrier groups {VMEM_READ x4}->{MFMA x16} pinning
// load-issue BEFORE each tile's MFMAs (compile-time only -- no runtime waits,
// unlike R11's vmcnt pinning which serialized). bounds(256,2): ~230 VGPR OK.
// (R13 == R14: the R13 bench died to an infra fault before running.)
__global__ __launch_bounds__(256, 2) void mlp_score(
    const float* __restrict__ x, const float* __restrict__ w1,
    const float* __restrict__ b1, const float* __restrict__ w2,
    const float* __restrict__ b2, float* __restrict__ score, int E)
{
    const int tid  = threadIdx.x;
    const int lane = tid & 63;
    const int wid  = tid >> 6;
    const int g    = lane >> 4;   // 0..3
    const int l15  = lane & 15;   // 0..15

    // ---- one-time: w1 A-fragments (64 VGPRs), RTN cvt
    half8 afr[2][8];
#pragma unroll
    for (int ks = 0; ks < 2; ++ks)
#pragma unroll
        for (int ct = 0; ct < 8; ++ct) {
            const float* wp = w1 + (size_t)(ks * 32 + g * 8) * HID + ct * 16 + l15;
            half8 h;
#pragma unroll
            for (int j = 0; j < 8; ++j) h[j] = (_Float16)wp[(size_t)j * HID];
            afr[ks][ct] = h;
        }

    // ---- one-time: bias-as-C and w2 fragments
    floatx4 biasC[8], w2r[8];
#pragma unroll
    for (int ct = 0; ct < 8; ++ct)
#pragma unroll
        for (int r = 0; r < 4; ++r) {
            biasC[ct][r] = b1[ct * 16 + g * 4 + r];
            w2r[ct][r]   = w2[ct * 16 + g * 4 + r];
        }
    const float b2v = b2[0];

    const int nwtile = E >> 4;                  // 16-edge tiles
    const int TOTW   = (int)gridDim.x * 4;      // total waves
    const int gw     = blockIdx.x * 4 + wid;
    const int n      = nwtile / TOTW;           // tiles per wave
    const int rem    = nwtile - n * TOTW;
    const size_t laneoff = (size_t)l15 * IN_CH + g * 8;

    union H8 { half8 h8; fp16x2 h2[4]; };

#define TIDX(I) (gw + (I) * TOTW)

#define LOADSET(F, T) do {                                            \
        const float* xr = x + (size_t)(T) * (16 * IN_CH) + laneoff;   \
        F##0 = *(const floatx4*)(xr);                                 \
        F##1 = *(const floatx4*)(xr + 4);                             \
        F##2 = *(const floatx4*)(xr + 32);                            \
        F##3 = *(const floatx4*)(xr + 36);                            \
    } while (0)

#define CORE(F, WT) do {                                              \
        H8 ub, uc;                                                    \
        ub.h2[0] = __builtin_amdgcn_cvt_pkrtz(F##0[0], F##0[1]);      \
        ub.h2[1] = __builtin_amdgcn_cvt_pkrtz(F##0[2], F##0[3]);      \
        ub.h2[2] = __builtin_amdgcn_cvt_pkrtz(F##1[0], F##1[1]);      \
        ub.h2[3] = __builtin_amdgcn_cvt_pkrtz(F##1[2], F##1[3]);      \
        uc.h2[0] = __builtin_amdgcn_cvt_pkrtz(F##2[0], F##2[1]);      \
        uc.h2[1] = __builtin_amdgcn_cvt_pkrtz(F##2[2], F##2[3]);      \
        uc.h2[2] = __builtin_amdgcn_cvt_pkrtz(F##3[0], F##3[1]);      \
        uc.h2[3] = __builtin_amdgcn_cvt_pkrtz(F##3[2], F##3[3]);      \
        floatx4 acc[8];                                               \
        _Pragma("unroll")                                             \
        for (int ct = 0; ct < 8; ++ct)                                \
            acc[ct] = __builtin_amdgcn_mfma_f32_16x16x32_f16(afr[0][ct], ub.h8, biasC[ct], 0, 0, 0); \
        _Pragma("unroll")                                             \
        for (int ct = 0; ct < 8; ++ct)                                \
            acc[ct] = __builtin_amdgcn_mfma_f32_16x16x32_f16(afr[1][ct], uc.h8, acc[ct], 0, 0, 0);   \
        float s0 = 0.f, s1 = 0.f, s2 = 0.f, s3 = 0.f;                 \
        _Pragma("unroll")                                             \
        for (int ct = 0; ct < 8; ++ct) {                              \
            s0 += fmaxf(acc[ct][0], 0.f) * w2r[ct][0];                \
            s1 += fmaxf(acc[ct][1], 0.f) * w2r[ct][1];                \
            s2 += fmaxf(acc[ct][2], 0.f) * w2r[ct][2];                \
            s3 += fmaxf(acc[ct][3], 0.f) * w2r[ct][3];                \
        }                                                             \
        float s = (s0 + s1) + (s2 + s3);                              \
        s += __shfl_xor(s, 16);                                       \
        s += __shfl_xor(s, 32);                                       \
        if (lane < 16)                                                \
            score[(size_t)(WT) * 16 + l15] = s + b2v;                 \
    } while (0)

// groups: issue the 4 prefetch loads FIRST, then this tile's 16 MFMAs.
#define SEG_PIN()  do {                                               \
        __builtin_amdgcn_sched_group_barrier(0x020, 4, 0);  /* VMEM_READ */ \
        __builtin_amdgcn_sched_group_barrier(0x008, 16, 0); /* MFMA */      \
    } while (0)

    int i = 0;
    if (n >= 2) {
        floatx4 A0, A1, A2, A3, B0, B1, B2, B3, C0, C1, C2, C3;
        LOADSET(A, TIDX(0));
        LOADSET(B, TIDX(1));
        for (; i + 5 < n; i += 3) {
            LOADSET(C, TIDX(i + 2));
            CORE(A, TIDX(i));
            SEG_PIN();
            LOADSET(A, TIDX(i + 3));
            CORE(B, TIDX(i + 1));
            SEG_PIN();
            LOADSET(B, TIDX(i + 4));
            CORE(C, TIDX(i + 2));
            SEG_PIN();
        }
        // invariant: A = tile i, B = tile i+1 (both loaded), i+5 >= n
        CORE(A, TIDX(i));
        if (i + 1 < n) CORE(B, TIDX(i + 1));
        i += 2;
    }
    for (; i < n; ++i) {          // serial tail (<=3 tiles)
        floatx4 T0, T1, T2, T3;
        LOADSET(T, TIDX(i));
        CORE(T, TIDX(i));
    }
    if (gw < rem) {   // remainder tiles (0 for E = 2^21)
        int wt_ = n * TOTW + gw;
        floatx4 R0, R1, R2, R3;
        LOADSET(R, wt_);
        CORE(R, wt_);
    }
#undef TIDX
#undef LOADSET
#undef CORE
#undef SEG_PIN
}

// ---------------- segment max (run-compressed atomics) ----------------
__global__ __launch_bounds__(256) void seg_max(
    const float* __restrict__ score, const int* __restrict__ batch,
    unsigned* __restrict__ segkey, int E)
{
    int t = blockIdx.x * 256 + threadIdx.x;
    int i0 = t * 8;
    if (i0 + 8 > E) return;
    int4 bA = *(const int4*)(batch + i0);
    int4 bB = *(const int4*)(batch + i0 + 4);
    floatx4 sA = *(const floatx4*)(score + i0);
    floatx4 sB = *(const floatx4*)(score + i0 + 4);
    int   ids[8] = {bA.x, bA.y, bA.z, bA.w, bB.x, bB.y, bB.z, bB.w};
    float ss[8]  = {sA[0], sA[1], sA[2], sA[3], sB[0], sB[1], sB[2], sB[3]};
    int cur = ids[0];
    float m = ss[0];
#pragma unroll
    for (int j = 1; j < 8; ++j) {
        if (ids[j] == cur) {
            m = fmaxf(m, ss[j]);
        } else {
            atomicMax(segkey + cur, fkey(m));
            cur = ids[j];
            m = ss[j];
        }
    }
    atomicMax(segkey + cur, fkey(m));
}

// ---------------- segment denom (run-compressed atomics) ----------------
__global__ __launch_bounds__(256) void seg_denom(
    const float* __restrict__ score, const int* __restrict__ batch,
    const unsigned* __restrict__ segkey, float* __restrict__ denom, int E)
{
    int t = blockIdx.x * 256 + threadIdx.x;
    int i0 = t * 8;
    if (i0 + 8 > E) return;
    int4 bA = *(const int4*)(batch + i0);
    int4 bB = *(const int4*)(batch + i0 + 4);
    floatx4 sA = *(const floatx4*)(score + i0);
    floatx4 sB = *(const floatx4*)(score + i0 + 4);
    int   ids[8] = {bA.x, bA.y, bA.z, bA.w, bB.x, bB.y, bB.z, bB.w};
    float ss[8]  = {sA[0], sA[1], sA[2], sA[3], sB[0], sB[1], sB[2], sB[3]};
    int cur = ids[0];
    float m = funkey(segkey[cur]);
    float a = __expf(ss[0] - m);
#pragma unroll
    for (int j = 1; j < 8; ++j) {
        if (ids[j] == cur) {
            a += __expf(ss[j] - m);
        } else {
            atomicAdd(denom + cur, a);
            cur = ids[j];
            m = funkey(segkey[cur]);
            a = __expf(ss[j] - m);
        }
    }
    atomicAdd(denom + cur, a);
}

// ---------------- finalize: out = exp(s-m)/(denom+eps), in place ----------------
__global__ __launch_bounds__(256) void finalize(
    float* __restrict__ score, const int* __restrict__ batch,
    const unsigned* __restrict__ segkey, const float* __restrict__ denom, int E)
{
    int t = blockIdx.x * 256 + threadIdx.x;
    int i0 = t * 8;
    if (i0 + 8 > E) return;
    int4 bA = *(const int4*)(batch + i0);
    int4 bB = *(const int4*)(batch + i0 + 4);
    floatx4 sA = *(const floatx4*)(score + i0);
    floatx4 sB = *(const floatx4*)(score + i0 + 4);
    int   ids[8] = {bA.x, bA.y, bA.z, bA.w, bB.x, bB.y, bB.z, bB.w};
    float ss[8]  = {sA[0], sA[1], sA[2], sA[3], sB[0], sB[1], sB[2], sB[3]};
    floatx4 oA, oB;
#pragma unroll
    for (int j = 0; j < 4; ++j) {
        float mj = funkey(segkey[ids[j]]);
        oA[j] = __expf(ss[j] - mj) / (denom[ids[j]] + 1e-16f);
    }
#pragma unroll
    for (int j = 0; j < 4; ++j) {
        float mj = funkey(segkey[ids[j + 4]]);
        oB[j] = __expf(ss[j + 4] - mj) / (denom[ids[j + 4]] + 1e-16f);
    }
    *(floatx4*)(score + i0)     = oA;
    *(floatx4*)(score + i0 + 4) = oB;
}

extern "C" void kernel_launch(void* const* d_in, const int* in_sizes, int n_in,
                              void* d_out, int out_size, void* d_ws, size_t ws_size,
                              hipStream_t stream) {
    const float* x   = (const float*)d_in[0];
    const float* w1  = (const float*)d_in[1];
    const float* b1  = (const float*)d_in[2];
    const float* w2  = (const float*)d_in[3];
    const float* b2  = (const float*)d_in[4];
    const int* batch = (const int*)d_in[5];
    float* out = (float*)d_out;
    const int E = in_sizes[5];

    unsigned* segkey = (unsigned*)d_ws;
    float*    denom  = (float*)((char*)d_ws + NSEG * sizeof(unsigned));

    init_seg<<<(NSEG + 255) / 256, 256, 0, stream>>>(segkey, denom);
    // scores are written into d_out (reused as scratch), finalized in place
    mlp_score<<<512, 256, 0, stream>>>(x, w1, b1, w2, b2, out, E);
    const int nthr = E / 8;
    seg_max   <<<nthr / 256, 256, 0, stream>>>(out, batch, segkey, E);
    seg_denom <<<nthr / 256, 256, 0, stream>>>(out, batch, segkey, denom, E);
    finalize  <<<nthr / 256, 256, 0, stream>>>(out, batch, segkey, denom, E);
}

// Round 18
// 188.112 us; speedup vs baseline: 1.0303x; 1.0303x over previous
//
#include <hip/hip_runtime.h>
#include <hip/hip_bf16.h>
#include <math.h>

typedef _Float16 half8  __attribute__((ext_vector_type(8)));
typedef __fp16   fp16x2 __attribute__((ext_vector_type(2)));
typedef float    floatx4 __attribute__((ext_vector_type(4)));

#define IN_CH 64
#define HID   128
#define NSEG  4096

__device__ __forceinline__ unsigned fkey(float s) {
    unsigned u = __float_as_uint(s);
    return (u & 0x80000000u) ? ~u : (u | 0x80000000u);
}
__device__ __forceinline__ float funkey(unsigned k) {
    unsigned u = (k & 0x80000000u) ? (k ^ 0x80000000u) : ~k;
    return __uint_as_float(u);
}

// ---------------- init segment scratch ----------------
__global__ void init_seg(unsigned* __restrict__ segkey, float* __restrict__ denom) {
    int i = blockIdx.x * blockDim.x + threadIdx.x;
    if (i < NSEG) { segkey[i] = 0u; denom[i] = 0.0f; }
}

// ---------------- fused MLP -> scores ----------------
// R6-verified swapped-operand MFMA core. R18 (4th submit of the R15 design;
// R15/R16/R17 all died to the same dead-pod infra fault, pre-upload, kernel
// never reached the container). The one untested {path x pattern} cell:
// PLAIN vector loads with PERFECT m13 coalescing (lane i reads contiguous
// bytes [i*16,i*16+16) of each 1KB chunk) + LDS bounce using the R9-verified
// XOR swizzle (woff as ds_write dest, roff reader unchanged). Two reg-sets
// P/Q + depth-4 LDS ring per wave: loads of tile i+2 issued before the
// ds_write of tile i+1 -> 2 tiles (8KB)/wave in HBM flight; compiler emits
// counted vmcnt from the reg dependency (no hand vmcnt -- R11 lesson).
// sched_group_barrier {VM4,DSR4,MFMA16,DSW4} stops load-sinking (R12 lesson).
__global__ __launch_bounds__(256, 2) void mlp_score(
    const float* __restrict__ x, const float* __restrict__ w1,
    const float* __restrict__ b1, const float* __restrict__ w2,
    const float* __restrict__ b2, float* __restrict__ score, int E)
{
    // [wave][ring 0..3][4KB tile: 16 rows x 256B, 16B units swizzled u = v^r]
    __shared__ __align__(16) char smem[4 * 4 * 4096];   // 64 KB

    const int tid  = threadIdx.x;
    const int lane = tid & 63;
    const int wid  = tid >> 6;
    const int g    = lane >> 4;   // 0..3
    const int l15  = lane & 15;   // 0..15
    const int ls4  = lane >> 4;

    // ---- one-time: w1 A-fragments (64 VGPRs), RTN cvt
    half8 afr[2][8];
#pragma unroll
    for (int ks = 0; ks < 2; ++ks)
#pragma unroll
        for (int ct = 0; ct < 8; ++ct) {
            const float* wp = w1 + (size_t)(ks * 32 + g * 8) * HID + ct * 16 + l15;
            half8 h;
#pragma unroll
            for (int j = 0; j < 8; ++j) h[j] = (_Float16)wp[(size_t)j * HID];
            afr[ks][ct] = h;
        }

    // ---- one-time: bias-as-C and w2 fragments
    floatx4 biasC[8], w2r[8];
#pragma unroll
    for (int ct = 0; ct < 8; ++ct)
#pragma unroll
        for (int r = 0; r < 4; ++r) {
            biasC[ct][r] = b1[ct * 16 + g * 4 + r];
            w2r[ct][r]   = w2[ct * 16 + g * 4 + r];
        }
    const float b2v = b2[0];

    const int nwtile = E >> 4;                  // 16-edge tiles
    const int TOTW   = (int)gridDim.x * 4;      // total waves
    const int gw     = blockIdx.x * 4 + wid;
    const int n      = nwtile / TOTW;           // tiles per wave
    const int rem    = nwtile - n * TOTW;

    char* lwave = smem + wid * 16384;
    const char* xb = (const char*)x;

    // writer LDS offsets: lane holds G[r][l15] of chunk c (r = c*4+ls4);
    // store at slot u = l15 ^ r  ->  woff[c] = r*256 + ((l15^r)&15)*16
    unsigned woff[4];
#pragma unroll
    for (int c = 0; c < 4; ++c) {
        int r = c * 4 + ls4;
        woff[c] = (unsigned)(r * 256 + ((l15 ^ r) & 15) * 16);
    }
    // reader (R9-verified): G[l15][v] lives at slot v^l15 of row l15
    const unsigned roff = (unsigned)(l15 * 256 + (((2 * g) ^ l15) & 15) * 16);

    union H8 { half8 h8; fp16x2 h2[4]; };

#define TIDX(I) (gw + (I) * TOTW)

// contiguous 1KB per instruction: lane reads [lane*16, lane*16+16) of chunk
#define LOADREG(F, T) do {                                                     \
        const char* gs = xb + (size_t)(T) * 4096 + lane * 16;                  \
        F##0 = *(const floatx4*)(gs);                                          \
        F##1 = *(const floatx4*)(gs + 1024);                                   \
        F##2 = *(const floatx4*)(gs + 2048);                                   \
        F##3 = *(const floatx4*)(gs + 3072);                                   \
    } while (0)

#define WLDS(BI, F) do {                                                       \
        char* lb_ = lwave + (BI) * 4096;                                       \
        *(floatx4*)(lb_ + woff[0]) = F##0;                                     \
        *(floatx4*)(lb_ + woff[1]) = F##1;                                     \
        *(floatx4*)(lb_ + woff[2]) = F##2;                                     \
        *(floatx4*)(lb_ + woff[3]) = F##3;                                     \
    } while (0)

#define CORE(F0_, F1_, F2_, F3_, WT) do {                                      \
        H8 ub, uc;                                                             \
        ub.h2[0] = __builtin_amdgcn_cvt_pkrtz(F0_[0], F0_[1]);                 \
        ub.h2[1] = __builtin_amdgcn_cvt_pkrtz(F0_[2], F0_[3]);                 \
        ub.h2[2] = __builtin_amdgcn_cvt_pkrtz(F1_[0], F1_[1]);                 \
        ub.h2[3] = __builtin_amdgcn_cvt_pkrtz(F1_[2], F1_[3]);                 \
        uc.h2[0] = __builtin_amdgcn_cvt_pkrtz(F2_[0], F2_[1]);                 \
        uc.h2[1] = __builtin_amdgcn_cvt_pkrtz(F2_[2], F2_[3]);                 \
        uc.h2[2] = __builtin_amdgcn_cvt_pkrtz(F3_[0], F3_[1]);                 \
        uc.h2[3] = __builtin_amdgcn_cvt_pkrtz(F3_[2], F3_[3]);                 \
        floatx4 acc[8];                                                        \
        _Pragma("unroll")                                                      \
        for (int ct = 0; ct < 8; ++ct)                                         \
            acc[ct] = __builtin_amdgcn_mfma_f32_16x16x32_f16(afr[0][ct], ub.h8, biasC[ct], 0, 0, 0); \
        _Pragma("unroll")                                                      \
        for (int ct = 0; ct < 8; ++ct)                                         \
            acc[ct] = __builtin_amdgcn_mfma_f32_16x16x32_f16(afr[1][ct], uc.h8, acc[ct], 0, 0, 0);   \
        float s0 = 0.f, s1 = 0.f, s2 = 0.f, s3 = 0.f;                          \
        _Pragma("unroll")                                                      \
        for (int ct = 0; ct < 8; ++ct) {                                       \
            s0 += fmaxf(acc[ct][0], 0.f) * w2r[ct][0];                         \
            s1 += fmaxf(acc[ct][1], 0.f) * w2r[ct][1];                         \
            s2 += fmaxf(acc[ct][2], 0.f) * w2r[ct][2];                         \
            s3 += fmaxf(acc[ct][3], 0.f) * w2r[ct][3];                         \
        }                                                                      \
        float s = (s0 + s1) + (s2 + s3);                                       \
        s += __shfl_xor(s, 16);                                                \
        s += __shfl_xor(s, 32);                                                \
        if (lane < 16)                                                         \
            score[(size_t)(WT) * 16 + l15] = s + b2v;                          \
    } while (0)

#define BODY(I) do {                                                           \
        const char* lb_ = lwave + ((I) & 3) * 4096;                            \
        floatx4 f0 = *(const floatx4*)(lb_ + roff);                            \
        floatx4 f1 = *(const floatx4*)(lb_ + (roff ^ 16u));                    \
        floatx4 f2 = *(const floatx4*)(lb_ + (roff ^ 128u));                   \
        floatx4 f3 = *(const floatx4*)(lb_ + (roff ^ 144u));                   \
        CORE(f0, f1, f2, f3, TIDX(I));                                         \
    } while (0)

// per-half-iteration pin: loads first, then tile ds_reads, MFMAs, ds_writes
#define PIN() do {                                                             \
        __builtin_amdgcn_sched_group_barrier(0x020, 4, 0);  /* VMEM_READ */    \
        __builtin_amdgcn_sched_group_barrier(0x100, 4, 0);  /* DS_READ  */     \
        __builtin_amdgcn_sched_group_barrier(0x008, 16, 0); /* MFMA     */     \
        __builtin_amdgcn_sched_group_barrier(0x200, 4, 0);  /* DS_WRITE */     \
    } while (0)

    int i = 0;
    if (n >= 6 && (n & 1) == 0) {
        floatx4 P0, P1, P2, P3, Q0, Q1, Q2, Q3;
        LOADREG(P, TIDX(0));
        LOADREG(Q, TIDX(1));
        WLDS(0, P);                    // waits P (vmcnt counted by compiler)
        LOADREG(P, TIDX(2));
        WLDS(1, Q);                    // waits Q
        // invariant (i even): bufs i,i+1 written; P = tile i+2 in flight
        for (i = 0; i + 4 < n; i += 2) {
            LOADREG(Q, TIDX(i + 3));
            BODY(i);
            WLDS((i + 2) & 3, P);
            PIN();
            LOADREG(P, TIDX(i + 4));
            BODY(i + 1);
            WLDS((i + 3) & 3, Q);
            PIN();
        }
        // i = n-4: bufs n-4,n-3 ready; P = tile n-2 in flight
        LOADREG(Q, TIDX(n - 1));
        BODY(n - 4);
        WLDS((n - 2) & 3, P);
        BODY(n - 3);
        WLDS((n - 1) & 3, Q);
        BODY(n - 2);
        BODY(n - 1);
        i = n;
    }
    for (; i < n; ++i) {               // serial fallback (not hit at E=2^21)
        floatx4 P0, P1, P2, P3;
        LOADREG(P, TIDX(i));
        WLDS(i & 3, P);
        BODY(i);
    }
    if (gw < rem) {                    // remainder (0 for E=2^21)
        int wt_ = n * TOTW + gw;
        floatx4 P0, P1, P2, P3;
        const char* gs = xb + (size_t)wt_ * 4096 + lane * 16;
        P0 = *(const floatx4*)(gs);
        P1 = *(const floatx4*)(gs + 1024);
        P2 = *(const floatx4*)(gs + 2048);
        P3 = *(const floatx4*)(gs + 3072);
        WLDS(0, P);
        const char* lb_ = lwave;
        floatx4 f0 = *(const floatx4*)(lb_ + roff);
        floatx4 f1 = *(const floatx4*)(lb_ + (roff ^ 16u));
        floatx4 f2 = *(const floatx4*)(lb_ + (roff ^ 128u));
        floatx4 f3 = *(const floatx4*)(lb_ + (roff ^ 144u));
        CORE(f0, f1, f2, f3, wt_);
    }
#undef TIDX
#undef LOADREG
#undef WLDS
#undef CORE
#undef BODY
#undef PIN
}

// ---------------- segment max (run-compressed atomics) ----------------
__global__ __launch_bounds__(256) void seg_max(
    const float* __restrict__ score, const int* __restrict__ batch,
    unsigned* __restrict__ segkey, int E)
{
    int t = blockIdx.x * 256 + threadIdx.x;
    int i0 = t * 8;
    if (i0 + 8 > E) return;
    int4 bA = *(const int4*)(batch + i0);
    int4 bB = *(const int4*)(batch + i0 + 4);
    floatx4 sA = *(const floatx4*)(score + i0);
    floatx4 sB = *(const floatx4*)(score + i0 + 4);
    int   ids[8] = {bA.x, bA.y, bA.z, bA.w, bB.x, bB.y, bB.z, bB.w};
    float ss[8]  = {sA[0], sA[1], sA[2], sA[3], sB[0], sB[1], sB[2], sB[3]};
    int cur = ids[0];
    float m = ss[0];
#pragma unroll
    for (int j = 1; j < 8; ++j) {
        if (ids[j] == cur) {
            m = fmaxf(m, ss[j]);
        } else {
            atomicMax(segkey + cur, fkey(m));
            cur = ids[j];
            m = ss[j];
        }
    }
    atomicMax(segkey + cur, fkey(m));
}

// ---------------- segment denom (run-compressed atomics) ----------------
__global__ __launch_bounds__(256) void seg_denom(
    const float* __restrict__ score, const int* __restrict__ batch,
    const unsigned* __restrict__ segkey, float* __restrict__ denom, int E)
{
    int t = blockIdx.x * 256 + threadIdx.x;
    int i0 = t * 8;
    if (i0 + 8 > E) return;
    int4 bA = *(const int4*)(batch + i0);
    int4 bB = *(const int4*)(batch + i0 + 4);
    floatx4 sA = *(const floatx4*)(score + i0);
    floatx4 sB = *(const floatx4*)(score + i0 + 4);
    int   ids[8] = {bA.x, bA.y, bA.z, bA.w, bB.x, bB.y, bB.z, bB.w};
    float ss[8]  = {sA[0], sA[1], sA[2], sA[3], sB[0], sB[1], sB[2], sB[3]};
    int cur = ids[0];
    float m = funkey(segkey[cur]);
    float a = __expf(ss[0] - m);
#pragma unroll
    for (int j = 1; j < 8; ++j) {
        if (ids[j] == cur) {
            a += __expf(ss[j] - m);
        } else {
            atomicAdd(denom + cur, a);
            cur = ids[j];
            m = funkey(segkey[cur]);
            a = __expf(ss[j] - m);
        }
    }
    atomicAdd(denom + cur, a);
}

// ---------------- finalize: out = exp(s-m)/(denom+eps), in place ----------------
__global__ __launch_bounds__(256) void finalize(
    float* __restrict__ score, const int* __restrict__ batch,
    const unsigned* __restrict__ segkey, const float* __restrict__ denom, int E)
{
    int t = blockIdx.x * 256 + threadIdx.x;
    int i0 = t * 8;
    if (i0 + 8 > E) return;
    int4 bA = *(const int4*)(batch + i0);
    int4 bB = *(const int4*)(batch + i0 + 4);
    floatx4 sA = *(const floatx4*)(score + i0);
    floatx4 sB = *(const floatx4*)(score + i0 + 4);
    int   ids[8] = {bA.x, bA.y, bA.z, bA.w, bB.x, bB.y, bB.z, bB.w};
    float ss[8]  = {sA[0], sA[1], sA[2], sA[3], sB[0], sB[1], sB[2], sB[3]};
    floatx4 oA, oB;
#pragma unroll
    for (int j = 0; j < 4; ++j) {
        float mj = funkey(segkey[ids[j]]);
        oA[j] = __expf(ss[j] - mj) / (denom[ids[j]] + 1e-16f);
    }
#pragma unroll
    for (int j = 0; j < 4; ++j) {
        float mj = funkey(segkey[ids[j + 4]]);
        oB[j] = __expf(ss[j + 4] - mj) / (denom[ids[j + 4]] + 1e-16f);
    }
    *(floatx4*)(score + i0)     = oA;
    *(floatx4*)(score + i0 + 4) = oB;
}

extern "C" void kernel_launch(void* const* d_in, const int* in_sizes, int n_in,
                              void* d_out, int out_size, void* d_ws, size_t ws_size,
                              hipStream_t stream) {
    const float* x   = (const float*)d_in[0];
    const float* w1  = (const float*)d_in[1];
    const float* b1  = (const float*)d_in[2];
    const float* w2  = (const float*)d_in[3];
    const float* b2  = (const float*)d_in[4];
    const int* batch = (const int*)d_in[5];
    float* out = (float*)d_out;
    const int E = in_sizes[5];

    unsigned* segkey = (unsigned*)d_ws;
    float*    denom  = (float*)((char*)d_ws + NSEG * sizeof(unsigned));

    init_seg<<<(NSEG + 255) / 256, 256, 0, stream>>>(segkey, denom);
    // scores are written into d_out (reused as scratch), finalized in place
    mlp_score<<<512, 256, 0, stream>>>(x, w1, b1, w2, b2, out, E);
    const int nthr = E / 8;
    seg_max   <<<nthr / 256, 256, 0, stream>>>(out, batch, segkey, E);
    seg_denom <<<nthr / 256, 256, 0, stream>>>(out, batch, segkey, denom, E);
    finalize  <<<nthr / 256, 256, 0, stream>>>(out, batch, segkey, denom, E);
}